// Round 9
// baseline (304.928 us; speedup 1.0000x reference)
//
#include <hip/hip_runtime.h>
#include <hip/hip_bf16.h>

typedef float f4 __attribute__((ext_vector_type(4)));
typedef float f32x4 __attribute__((ext_vector_type(4)));
typedef unsigned short u16x8 __attribute__((ext_vector_type(8)));
typedef short short8 __attribute__((ext_vector_type(8)));
typedef unsigned int uint2v __attribute__((ext_vector_type(2)));

#define QSCALE 0.17677669529663689f  // 32^-0.5

__device__ inline float b2f(unsigned short u){
  union{unsigned int i; float f;} z; z.i = ((unsigned int)u)<<16; return z.f;
}
__device__ inline unsigned short f2b(float f){
  union{float f; unsigned int i;} z; z.f=f;
  unsigned int i = z.i;
  return (unsigned short)((i + 0x7FFFu + ((i>>16)&1u)) >> 16);
}

// stage a [128k][128n] fp32 weight panel -> Ws[n][k] bf16, XOR-swizzled (512 thr)
__device__ inline void stageW(const float* __restrict__ w, int stride, int n0,
                              short* Ws, int t){
  for (int c = t; c < 1024; c += 512){
    int kb = c >> 5, nb = c & 31;
    const float* p = &w[(kb*4)*stride + n0 + nb*4];
    f4 r0 = *(const f4*)p;
    f4 r1 = *(const f4*)(p + stride);
    f4 r2 = *(const f4*)(p + 2*stride);
    f4 r3 = *(const f4*)(p + 3*stride);
#pragma unroll
    for (int j = 0; j < 4; ++j){
      int n = nb*4 + j;
      uint2v val;
      val[0] = (unsigned int)f2b(r0[j]) | ((unsigned int)f2b(r1[j])<<16);
      val[1] = (unsigned int)f2b(r2[j]) | ((unsigned int)f2b(r3[j])<<16);
      int byte = (n<<8) + (kb<<3);
      *(uint2v*)((char*)Ws + (byte ^ ((n&7)<<4))) = val;
    }
  }
}

__device__ inline short8 ldB(const short* Ws, int rn, int koff){
  int byte = (rn<<8) + (koff<<1);
  return *(const short8*)((const char*)Ws + (byte ^ ((rn&7)<<4)));
}

__device__ inline short8 ldA(const float* p){
  f4 lo = *(const f4*)p, hi = *(const f4*)(p+4);
  short8 r;
  r[0]=(short)f2b(lo[0]); r[1]=(short)f2b(lo[1]);
  r[2]=(short)f2b(lo[2]); r[3]=(short)f2b(lo[3]);
  r[4]=(short)f2b(hi[0]); r[5]=(short)f2b(hi[1]);
  r[6]=(short)f2b(hi[2]); r[7]=(short)f2b(hi[3]);
  return r;
}

// ============ fully fused neighborhood attention, 8 waves/block ============
// grid (8,8,4) = (tile_j, tile_i, batch), block 512 (8 waves), 1 block/CU.
// Attention uses ONLINE softmax per thread so the live set (~75 VGPR) fits
// even if the allocator budgets 128 (it ignored both launch_bounds forms,
// r7/r8: 45/41 MB scratch spill). waves_per_eu(2,2) pins the occupancy
// target to what the 160KB LDS forces anyway.
__global__ __launch_bounds__(512)
__attribute__((amdgpu_waves_per_eu(2, 2)))
void k_fused(
    const float* __restrict__ x,     const float* __restrict__ wqkv,
    const float* __restrict__ bqkv,  const float* __restrict__ rpb,
    const float* __restrict__ wproj, const float* __restrict__ bproj,
    float* __restrict__ out)
{
  __shared__ short lds[79752];           // 159,504 B
  short* Qs = lds;                       // [64][136]  q, later ao
  short* Ks = lds + 8704;                // [196][136] k halo
  short* Vs = Ks + 26656;                // [196][136] v halo, later fp32 C
  short* Ws = Vs + 26656;                // [128][128] swizzled weight panel
  float* rs = (float*)(Ws + 16384);      // [676] rpb

  const int t  = threadIdx.x;
  const int b  = blockIdx.z;
  const int th0 = blockIdx.y * 8, tw0 = blockIdx.x * 8;
  const int bi0 = min(max(th0-3,0),50), bj0 = min(max(tw0-3,0),50);
  const int wv = t >> 6, l = t & 63;
  const int lr = l & 15, lk = (l >> 4) << 3;

  // phase 0: stage wq panel + rpb
  stageW(wqkv, 384, 0, Ws, t);
  for (int c = t; c < 676; c += 512) rs[c] = rpb[c];
  __syncthreads();                                          // S1

  // ---- Q GEMM: wave = (m-frag wv>>1, n-half wv&1), acc[4] ----
  {
    const int mq = wv >> 1, g = wv & 1;
    int ct = mq*16 + lr;
    const float* ax = x + ((b*64 + th0 + (ct>>3))*64 + tw0 + (ct&7))*128;
    f32x4 acc[4] = {};
#pragma unroll
    for (int k0 = 0; k0 < 4; ++k0){
      int koff = k0*32 + lk;
      short8 a = ldA(ax + koff);
#pragma unroll
      for (int fn = 0; fn < 4; ++fn)
        acc[fn] = __builtin_amdgcn_mfma_f32_16x16x32_bf16(a, ldB(Ws, (g*4+fn)*16+lr, koff), acc[fn], 0, 0, 0);
    }
#pragma unroll
    for (int fn = 0; fn < 4; ++fn){
      int col = (g*4+fn)*16 + lr;
      float bv = bqkv[col];
#pragma unroll
      for (int r = 0; r < 4; ++r){
        int row = mq*16 + ((l>>4)<<2) + r;
        Qs[row*136 + col] = f2b((acc[fn][r] + bv) * QSCALE);
      }
    }
  }
  __syncthreads();                                          // S2
  stageW(wqkv, 384, 128, Ws, t);
  __syncthreads();                                          // S3

  // ---- K GEMM: 13 M-frags; wave wv does frags {wv, wv+8} ----
#pragma unroll
  for (int pass = 0; pass < 2; ++pass){
    int fmi = wv + pass*8;
    if (fmi < 13){
      int tok = fmi*16 + lr; tok = tok < 196 ? tok : 195;
      int hr = tok/14, hc = tok - hr*14;
      const float* ax = x + ((b*64 + bi0+hr)*64 + bj0+hc)*128;
      f32x4 acc[8] = {};
#pragma unroll
      for (int k0 = 0; k0 < 4; ++k0){
        int koff = k0*32 + lk;
        short8 a = ldA(ax + koff);
#pragma unroll
        for (int fn = 0; fn < 8; ++fn)
          acc[fn] = __builtin_amdgcn_mfma_f32_16x16x32_bf16(a, ldB(Ws, fn*16+lr, koff), acc[fn], 0, 0, 0);
      }
#pragma unroll
      for (int fn = 0; fn < 8; ++fn){
        int col = fn*16 + lr;
        float bv = bqkv[128 + col];
#pragma unroll
        for (int r = 0; r < 4; ++r){
          int row = fmi*16 + ((l>>4)<<2) + r;
          if (row < 196) Ks[row*136 + col] = f2b(acc[fn][r] + bv);
        }
      }
    }
  }
  __syncthreads();                                          // S4
  stageW(wqkv, 384, 256, Ws, t);
  __syncthreads();                                          // S5

  // ---- V GEMM ----
#pragma unroll
  for (int pass = 0; pass < 2; ++pass){
    int fmi = wv + pass*8;
    if (fmi < 13){
      int tok = fmi*16 + lr; tok = tok < 196 ? tok : 195;
      int hr = tok/14, hc = tok - hr*14;
      const float* ax = x + ((b*64 + bi0+hr)*64 + bj0+hc)*128;
      f32x4 acc[8] = {};
#pragma unroll
      for (int k0 = 0; k0 < 4; ++k0){
        int koff = k0*32 + lk;
        short8 a = ldA(ax + koff);
#pragma unroll
        for (int fn = 0; fn < 8; ++fn)
          acc[fn] = __builtin_amdgcn_mfma_f32_16x16x32_bf16(a, ldB(Ws, fn*16+lr, koff), acc[fn], 0, 0, 0);
      }
#pragma unroll
      for (int fn = 0; fn < 8; ++fn){
        int col = fn*16 + lr;
        float bv = bqkv[256 + col];
#pragma unroll
        for (int r = 0; r < 4; ++r){
          int row = fmi*16 + ((l>>4)<<2) + r;
          if (row < 196) Vs[row*136 + col] = f2b(acc[fn][r] + bv);
        }
      }
    }
  }
  __syncthreads();                                          // S6a

  // stage w_proj; latency hides under attention
  stageW(wproj, 128, 0, Ws, t);

  // ---- attention: thread = (token lt, head h, parity p), ONLINE softmax ----
  const int lt = t >> 3, h = (t >> 1) & 3, p = t & 1;
  const int ti = th0 + (lt >> 3), tj = tw0 + (lt & 7);
  const int si = min(max(ti-3,0),57), sj = min(max(tj-3,0),57);
  const int li = si - bi0, lj = sj - bj0;
  const int ri = si - ti + 6, rj = sj - tj + 6;
  const int tbase = li*14 + lj;
  const int rbase = h*169 + ri*13 + rj;

  float q[32];
#pragma unroll
  for (int j = 0; j < 4; ++j){
    u16x8 u = *(const u16x8*)&Qs[lt*136 + h*32 + j*8];
#pragma unroll
    for (int e = 0; e < 8; ++e) q[j*8+e] = b2f(u[e]);
  }
  __syncthreads();                          // S6b: all q reads done; Qs free

  float m = -1e30f, lsum = 0.f, o[32];
#pragma unroll
  for (int d = 0; d < 32; ++d) o[d] = 0.f;
#pragma unroll
  for (int it = 0; it < 25; ++it){
    int n = p + (it << 1);
    bool ok = (n < 49);
    int nn = ok ? n : 48;
    int pi = nn / 7, pj = nn - pi*7;
    int tok = tbase + pi*14 + pj;
    float acc = rs[rbase + pi*13 + pj];
#pragma unroll
    for (int j = 0; j < 4; ++j){
      u16x8 kk = *(const u16x8*)&Ks[tok*136 + h*32 + j*8];
#pragma unroll
      for (int e = 0; e < 8; ++e) acc += q[j*8+e]*b2f(kk[e]);
    }
    float s = ok ? acc : -1e30f;
    float mn = fmaxf(m, s);
    float sc = __expf(m - mn);
    float e  = __expf(s - mn);
    lsum = lsum*sc + e;
#pragma unroll
    for (int j = 0; j < 4; ++j){
      u16x8 vvv = *(const u16x8*)&Vs[tok*136 + h*32 + j*8];
#pragma unroll
      for (int e2 = 0; e2 < 8; ++e2){
        int d = j*8 + e2;
        o[d] = o[d]*sc + e*b2f(vvv[e2]);
      }
    }
    m = mn;
  }
  // merge the two parity halves (lanes differing in bit 0)
  {
    float m2 = __shfl_xor(m, 1);
    float mn = fmaxf(m, m2);
    float sc = __expf(m - mn);
    lsum *= sc;
    lsum += __shfl_xor(lsum, 1);
#pragma unroll
    for (int d = 0; d < 32; ++d) o[d] *= sc;
#pragma unroll
    for (int d = 0; d < 32; ++d) o[d] += __shfl_xor(o[d], 1);
  }
  float inv = 1.f / lsum;
#pragma unroll
  for (int j = 0; j < 2; ++j){
    u16x8 w8;
#pragma unroll
    for (int e = 0; e < 8; ++e) w8[e] = f2b(o[p*16 + j*8 + e]*inv);
    *(u16x8*)&Qs[lt*136 + h*32 + p*16 + j*8] = w8;          // ao -> Qs
  }
  __syncthreads();                                          // S7

  // ---- proj GEMM: wave = (m-frag wv>>1, n-half wv&1) ----
  {
    const int mq = wv >> 1, g = wv & 1;
    f32x4 acc[4] = {};
#pragma unroll
    for (int k0 = 0; k0 < 4; ++k0){
      int koff = k0*32 + lk;
      short8 a = *(const short8*)&Qs[(mq*16 + lr)*136 + koff];
#pragma unroll
      for (int fn = 0; fn < 4; ++fn)
        acc[fn] = __builtin_amdgcn_mfma_f32_16x16x32_bf16(a, ldB(Ws, (g*4+fn)*16+lr, koff), acc[fn], 0, 0, 0);
    }
    float* C = (float*)Vs;   // [64][132] fp32
#pragma unroll
    for (int fn = 0; fn < 4; ++fn){
      int col = (g*4+fn)*16 + lr;
      float bv = bproj[col];
#pragma unroll
      for (int r = 0; r < 4; ++r){
        int row = mq*16 + ((l>>4)<<2) + r;
        C[row*132 + col] = acc[fn][r] + bv;
      }
    }
  }
  __syncthreads();                                          // S8
  {
    float* C = (float*)Vs;
    for (int c = t; c < 2048; c += 512){
      int row = c >> 5, colc = (c & 31) << 2;
      int gtok = ((b*64 + th0 + (row>>3))*64 + tw0 + (row&7))*128;
      *(f4*)&out[gtok + colc] = *(const f4*)&C[row*132 + colc];
    }
  }
}

extern "C" void kernel_launch(void* const* d_in, const int* in_sizes, int n_in,
                              void* d_out, int out_size, void* d_ws, size_t ws_size,
                              hipStream_t stream) {
  const float* x      = (const float*)d_in[0];
  const float* w_qkv  = (const float*)d_in[1];
  const float* b_qkv  = (const float*)d_in[2];
  const float* rpb    = (const float*)d_in[3];
  const float* w_proj = (const float*)d_in[4];
  const float* b_proj = (const float*)d_in[5];
  float* out = (float*)d_out;

  k_fused<<<dim3(8, 8, 4), 512, 0, stream>>>(x, w_qkv, b_qkv, rpb, w_proj, b_proj, out);
}

// Round 12
// 148.237 us; speedup vs baseline: 2.0570x; 2.0570x over previous
//
#include <hip/hip_runtime.h>
#include <hip/hip_bf16.h>

typedef float f4 __attribute__((ext_vector_type(4)));
typedef float f32x4 __attribute__((ext_vector_type(4)));
typedef unsigned short u16x8 __attribute__((ext_vector_type(8)));
typedef short short8 __attribute__((ext_vector_type(8)));
typedef unsigned int uint2v __attribute__((ext_vector_type(2)));

#define QSCALE 0.17677669529663689f  // 32^-0.5
#define NBLK 512u

__device__ inline float b2f(unsigned short u){
  union{unsigned int i; float f;} z; z.i = ((unsigned int)u)<<16; return z.f;
}
__device__ inline unsigned short f2b(float f){
  union{float f; unsigned int i;} z; z.f=f;
  unsigned int i = z.i;
  return (unsigned short)((i + 0x7FFFu + ((i>>16)&1u)) >> 16);
}

__device__ inline short8 ldB(const short* Ws, int rn, int koff){
  int byte = (rn<<8) + (koff<<1);
  return *(const short8*)((const char*)Ws + (byte ^ ((rn&7)<<4)));
}

// all-resident grid barrier. Deadlock-free ONLY because launch_bounds(256,2)
// caps VGPR at 256 -> 8 waves/CU -> 2 blocks/CU x 256 CUs = 512 = grid size.
__device__ inline void grid_barrier(unsigned int* cnt){
  __syncthreads();
  if (threadIdx.x == 0){
    __threadfence();
    atomicAdd(cnt, 1u);
    while (atomicAdd(cnt, 0u) < NBLK) { }
    __threadfence();
  }
  __syncthreads();
}

// ============ fused 3-phase pipeline, manual grid sync ============
// grid 512 x 256 threads (4 waves), LDS 32.8 KB, 2 blocks/CU.
__global__ __launch_bounds__(256, 2) void k_pipe(
    const float* __restrict__ x,     const float* __restrict__ wqkv,
    const float* __restrict__ bqkv,  const float* __restrict__ rpb,
    const float* __restrict__ wproj, const float* __restrict__ bproj,
    float* __restrict__ out,
    unsigned short* __restrict__ qo, unsigned short* __restrict__ ko,
    unsigned short* __restrict__ vo, unsigned short* __restrict__ ao,
    unsigned int* __restrict__ cnt)
{
  __shared__ short smem[16384];                 // 32,768 B
  const int t  = threadIdx.x;
  const int bid = blockIdx.x;
  const int wv = t >> 6, l = t & 63;
  const int lr = l & 15, lk = (l >> 4) << 3;

  // ======== phase 1: qkv = x @ w_qkv + b_qkv, 1536 units of 64m x 64n ========
  {
    short* As = smem;            // [64][128] bf16 swizzled
    short* Bs = smem + 8192;     // [64 n][128 k] bf16 swizzled
#pragma unroll 1
    for (int k3 = 0; k3 < 3; ++k3){
      int u = bid + k3*512;
      int m0 = (u & 255) << 6;
      int rest = u >> 8;                 // 0..5
      int plane = rest >> 1, nh = rest & 1;
      int n0 = plane*128 + nh*64;
      for (int c = t; c < 1024; c += 256){
        int row = c >> 4, k0 = (c & 15) << 3;
        const float* p = &x[(m0+row)*128 + k0];
        f4 lo = *(const f4*)p, hi = *(const f4*)(p+4);
        u16x8 v;
        v[0]=f2b(lo[0]); v[1]=f2b(lo[1]); v[2]=f2b(lo[2]); v[3]=f2b(lo[3]);
        v[4]=f2b(hi[0]); v[5]=f2b(hi[1]); v[6]=f2b(hi[2]); v[7]=f2b(hi[3]);
        int byte = (row<<8) + (k0<<1);
        *(u16x8*)((char*)As + (byte ^ ((row&7)<<4))) = v;
      }
      for (int c = t; c < 512; c += 256){
        int kb = c >> 4, nb = c & 15;
        const float* p = &wqkv[(kb*4)*384 + n0 + nb*4];
        f4 r0 = *(const f4*)p;
        f4 r1 = *(const f4*)(p + 384);
        f4 r2 = *(const f4*)(p + 768);
        f4 r3 = *(const f4*)(p + 1152);
#pragma unroll
        for (int j = 0; j < 4; ++j){
          int n = nb*4 + j;
          uint2v val;
          val[0] = (unsigned int)f2b(r0[j]) | ((unsigned int)f2b(r1[j])<<16);
          val[1] = (unsigned int)f2b(r2[j]) | ((unsigned int)f2b(r3[j])<<16);
          int byte = (n<<8) + (kb<<3);
          *(uint2v*)((char*)Bs + (byte ^ ((n&7)<<4))) = val;
        }
      }
      __syncthreads();
      f32x4 acc[4] = {};
#pragma unroll
      for (int k0 = 0; k0 < 4; ++k0){
        int koff = k0*32 + lk;
        int row = wv*16 + lr;
        int byte = (row<<8) + (koff<<1);
        short8 a = *(const short8*)((const char*)As + (byte ^ ((row&7)<<4)));
#pragma unroll
        for (int fn = 0; fn < 4; ++fn)
          acc[fn] = __builtin_amdgcn_mfma_f32_16x16x32_bf16(a, ldB(Bs, fn*16+lr, koff), acc[fn], 0, 0, 0);
      }
      __syncthreads();
      short* C = As;                       // [64][72] bf16
      float scale = (plane == 0) ? QSCALE : 1.0f;
#pragma unroll
      for (int fn = 0; fn < 4; ++fn){
        int col = fn*16 + lr;
        float bv = bqkv[n0 + col];
#pragma unroll
        for (int r = 0; r < 4; ++r){
          int row = wv*16 + ((l>>4)<<2) + r;
          C[row*72 + col] = f2b((acc[fn][r] + bv) * scale);
        }
      }
      __syncthreads();
      unsigned short* dst = plane==0 ? qo : (plane==1 ? ko : vo);
      for (int c = t; c < 512; c += 256){
        int row = c >> 3, cc = (c & 7) << 3;
        int ch = nh*64 + cc;
        int head = ch >> 5, d0 = ch & 31;
        *(u16x8*)&dst[(head*16384 + m0 + row)*32 + d0] = *(u16x8*)&C[row*72 + cc];
      }
      __syncthreads();
    }
  }
  grid_barrier(&cnt[0]);

  // ======== phase 2: attention, 1024 units (tile, batch, head) ========
  {
    unsigned short* ks = (unsigned short*)smem;           // [196][40]
    unsigned short* vs = (unsigned short*)smem + 7840;    // [196][40]
    float* rs = (float*)((unsigned short*)smem + 15680);  // [169]
#pragma unroll 1
    for (int k2 = 0; k2 < 2; ++k2){
      int u = bid + k2*512;
      int b = u >> 8, h = (u >> 6) & 3, ty = (u >> 3) & 7, tx = u & 7;
      int th0 = ty*8, tw0 = tx*8;
      int bi0 = min(max(th0-3,0),50), bj0 = min(max(tw0-3,0),50);
      const unsigned short* kpb = ko + (h*16384 + b*4096)*32;
      const unsigned short* vpb = vo + (h*16384 + b*4096)*32;
      for (int c = t; c < 784; c += 256){
        int tok = c >> 2, ch = c & 3;
        int trow = tok/14, tcol = tok - trow*14;
        int g = ((bi0+trow)*64 + (bj0+tcol))*32 + ch*8;
        int lo2 = tok*40 + ch*8;
        *(u16x8*)&ks[lo2] = *(const u16x8*)&kpb[g];
        *(u16x8*)&vs[lo2] = *(const u16x8*)&vpb[g];
      }
      for (int c = t; c < 169; c += 256) rs[c] = rpb[h*169 + c];
      __syncthreads();

      const int lt = t >> 2, p = t & 3;
      const int ti = th0 + (lt >> 3), tj = tw0 + (lt & 7);
      const int si = min(max(ti-3,0),57), sj = min(max(tj-3,0),57);
      const int li = si - bi0, lj = sj - bj0;
      const int ri = si - ti + 6, rj = sj - tj + 6;
      const int tbase = li*14 + lj;
      const int rbase = ri*13 + rj;

      float q[32];
      {
        int qb = (h*16384 + b*4096 + ti*64 + tj)*32;
#pragma unroll
        for (int j = 0; j < 4; ++j){
          u16x8 uq = *(const u16x8*)&qo[qb + j*8];
#pragma unroll
          for (int e = 0; e < 8; ++e) q[j*8+e] = b2f(uq[e]);
        }
      }
      float s[13];
      float mx = -1e30f;
#pragma unroll
      for (int it = 0; it < 13; ++it){
        int n = p + (it << 2);
        bool ok = (n < 49);
        int nn = ok ? n : 48;
        int pi = nn / 7, pj = nn - pi*7;
        int tok = tbase + pi*14 + pj;
        float acc = rs[rbase + pi*13 + pj];
#pragma unroll
        for (int j = 0; j < 4; ++j){
          u16x8 kk = *(const u16x8*)&ks[tok*40 + j*8];
#pragma unroll
          for (int e = 0; e < 8; ++e) acc += q[j*8+e]*b2f(kk[e]);
        }
        s[it] = ok ? acc : -1e30f;
        mx = fmaxf(mx, s[it]);
      }
      mx = fmaxf(mx, __shfl_xor(mx, 1));
      mx = fmaxf(mx, __shfl_xor(mx, 2));

      float lsum = 0.f, o[32];
#pragma unroll
      for (int d = 0; d < 32; ++d) o[d] = 0.f;
#pragma unroll
      for (int it = 0; it < 13; ++it){
        int n = p + (it << 2);
        int nn = n < 49 ? n : 48;
        int pi = nn / 7, pj = nn - pi*7;
        int tok = tbase + pi*14 + pj;             // recomputed, saves 13 VGPR
        float e = __expf(s[it] - mx);
        lsum += e;
#pragma unroll
        for (int j = 0; j < 4; ++j){
          u16x8 vvv = *(const u16x8*)&vs[tok*40 + j*8];
#pragma unroll
          for (int e2 = 0; e2 < 8; ++e2) o[j*8+e2] += e*b2f(vvv[e2]);
        }
      }
      lsum += __shfl_xor(lsum, 1);
      lsum += __shfl_xor(lsum, 2);
#pragma unroll
      for (int d = 0; d < 32; ++d) o[d] += __shfl_xor(o[d], 1);
#pragma unroll
      for (int d = 0; d < 32; ++d) o[d] += __shfl_xor(o[d], 2);

      float inv = 1.f / lsum;
      {
        u16x8 w8;
#pragma unroll
        for (int e = 0; e < 8; ++e) w8[e] = f2b(o[p*8+e]*inv);
        *(u16x8*)&ao[(b*4096 + ti*64 + tj)*128 + h*32 + p*8] = w8;
      }
      __syncthreads();
    }
  }
  grid_barrier(&cnt[1]);

  // ======== phase 3: out = ao @ w_proj + b_proj, 512 units ========
  {
    int m0 = (bid >> 1) << 6, nh = bid & 1, n0 = nh << 6;
    short* As = smem;
    short* Bs = smem + 8192;
    for (int c = t; c < 1024; c += 256){
      int row = c >> 4, k0 = (c & 15) << 3;
      u16x8 v = *(const u16x8*)&ao[(m0+row)*128 + k0];
      int byte = (row<<8) + (k0<<1);
      *(u16x8*)((char*)As + (byte ^ ((row&7)<<4))) = v;
    }
    for (int c = t; c < 512; c += 256){
      int kb = c >> 4, nb = c & 15;
      const float* p = &wproj[(kb*4)*128 + n0 + nb*4];
      f4 r0 = *(const f4*)p;
      f4 r1 = *(const f4*)(p + 128);
      f4 r2 = *(const f4*)(p + 256);
      f4 r3 = *(const f4*)(p + 384);
#pragma unroll
      for (int j = 0; j < 4; ++j){
        int n = nb*4 + j;
        uint2v val;
        val[0] = (unsigned int)f2b(r0[j]) | ((unsigned int)f2b(r1[j])<<16);
        val[1] = (unsigned int)f2b(r2[j]) | ((unsigned int)f2b(r3[j])<<16);
        int byte = (n<<8) + (kb<<3);
        *(uint2v*)((char*)Bs + (byte ^ ((n&7)<<4))) = val;
      }
    }
    __syncthreads();
    f32x4 acc[4] = {};
#pragma unroll
    for (int k0 = 0; k0 < 4; ++k0){
      int koff = k0*32 + lk;
      int row = wv*16 + lr;
      int byte = (row<<8) + (koff<<1);
      short8 a = *(const short8*)((const char*)As + (byte ^ ((row&7)<<4)));
#pragma unroll
      for (int fn = 0; fn < 4; ++fn)
        acc[fn] = __builtin_amdgcn_mfma_f32_16x16x32_bf16(a, ldB(Bs, fn*16+lr, koff), acc[fn], 0, 0, 0);
    }
    __syncthreads();
    float* C = (float*)smem;   // [64][68] fp32
#pragma unroll
    for (int fn = 0; fn < 4; ++fn){
      int col = fn*16 + lr;
      float bv = bproj[n0 + col];
#pragma unroll
      for (int r = 0; r < 4; ++r){
        int row = wv*16 + ((l>>4)<<2) + r;
        C[row*68 + col] = acc[fn][r] + bv;
      }
    }
    __syncthreads();
    for (int c = t; c < 1024; c += 256){
      int row = c >> 4, colc = (c & 15) << 2;
      *(f4*)&out[(m0+row)*128 + n0 + colc] = *(const f4*)&C[row*68 + colc];
    }
  }
}

extern "C" void kernel_launch(void* const* d_in, const int* in_sizes, int n_in,
                              void* d_out, int out_size, void* d_ws, size_t ws_size,
                              hipStream_t stream) {
  const float* x      = (const float*)d_in[0];
  const float* wqkv   = (const float*)d_in[1];
  const float* bqkv   = (const float*)d_in[2];
  const float* rpb    = (const float*)d_in[3];
  const float* wproj  = (const float*)d_in[4];
  const float* bproj  = (const float*)d_in[5];
  float* out = (float*)d_out;

  unsigned short* qo = (unsigned short*)d_ws;          // [4 head][16384 tok][32]
  unsigned short* ko = qo + 16384*32*4;
  unsigned short* vo = ko + 16384*32*4;
  unsigned short* ao = vo + 16384*32*4;                // [16384 tok][128]
  unsigned int*  cnt = (unsigned int*)(ao + 16384*128);

  hipMemsetAsync(cnt, 0, 2*sizeof(unsigned int), stream);
  k_pipe<<<512, 256, 0, stream>>>(x, wqkv, bqkv, rpb, wproj, bproj, out,
                                  qo, ko, vo, ao, cnt);
}

// Round 13
// 144.493 us; speedup vs baseline: 2.1103x; 1.0259x over previous
//
#include <hip/hip_runtime.h>
#include <hip/hip_bf16.h>

typedef float f4 __attribute__((ext_vector_type(4)));
typedef float f32x4 __attribute__((ext_vector_type(4)));
typedef unsigned short u16x8 __attribute__((ext_vector_type(8)));
typedef short short8 __attribute__((ext_vector_type(8)));
typedef unsigned int uint2v __attribute__((ext_vector_type(2)));

#define QSCALE 0.17677669529663689f  // 32^-0.5
#define NBLK 512u

__device__ inline float b2f(unsigned short u){
  union{unsigned int i; float f;} z; z.i = ((unsigned int)u)<<16; return z.f;
}
__device__ inline unsigned short f2b(float f){
  union{float f; unsigned int i;} z; z.f=f;
  unsigned int i = z.i;
  return (unsigned short)((i + 0x7FFFu + ((i>>16)&1u)) >> 16);
}

__device__ inline short8 ldB(const short* Ws, int rn, int koff){
  int byte = (rn<<8) + (koff<<1);
  return *(const short8*)((const char*)Ws + (byte ^ ((rn&7)<<4)));
}

// all-resident grid barrier (512 blocks, capacity 4 blocks/CU -> co-resident).
// Poll via agent-scope atomic LOAD (no RMW serialization) + s_sleep backoff.
__device__ inline void grid_barrier(unsigned int* cnt){
  __syncthreads();
  if (threadIdx.x == 0){
    __threadfence();
    atomicAdd(cnt, 1u);
    while (__hip_atomic_load(cnt, __ATOMIC_RELAXED, __HIP_MEMORY_SCOPE_AGENT) < NBLK)
      __builtin_amdgcn_s_sleep(8);
    __threadfence();
  }
  __syncthreads();
}

// ============ fused 3-phase pipeline, manual grid sync ============
// grid 512 x 256 threads (4 waves), LDS 37.4 KB, 2+ blocks/CU.
__global__ __launch_bounds__(256, 2) void k_pipe(
    const float* __restrict__ x,     const float* __restrict__ wqkv,
    const float* __restrict__ bqkv,  const float* __restrict__ rpb,
    const float* __restrict__ wproj, const float* __restrict__ bproj,
    float* __restrict__ out,
    unsigned short* __restrict__ qo, unsigned short* __restrict__ ko,
    unsigned short* __restrict__ vo, unsigned short* __restrict__ ao,
    unsigned int* __restrict__ cnt)
{
  __shared__ short smem[18688];                 // 37,376 B
  const int t  = threadIdx.x;
  const int bid = blockIdx.x;
  const int wv = t >> 6, l = t & 63;
  const int lr = l & 15, lk = (l >> 4) << 3;

  // ======== phase 1: qkv = x @ w_qkv + b_qkv, 1536 units of 64m x 64n ========
  {
    short* As = smem;            // [64][128] bf16 swizzled
    short* Bs = smem + 8192;     // [64 n][128 k] bf16 swizzled
#pragma unroll 1
    for (int k3 = 0; k3 < 3; ++k3){
      int u = bid + k3*512;
      int m0 = (u & 255) << 6;
      int rest = u >> 8;                 // 0..5
      int plane = rest >> 1, nh = rest & 1;
      int n0 = plane*128 + nh*64;
      for (int c = t; c < 1024; c += 256){
        int row = c >> 4, k0 = (c & 15) << 3;
        const float* p = &x[(m0+row)*128 + k0];
        f4 lo = *(const f4*)p, hi = *(const f4*)(p+4);
        u16x8 v;
        v[0]=f2b(lo[0]); v[1]=f2b(lo[1]); v[2]=f2b(lo[2]); v[3]=f2b(lo[3]);
        v[4]=f2b(hi[0]); v[5]=f2b(hi[1]); v[6]=f2b(hi[2]); v[7]=f2b(hi[3]);
        int byte = (row<<8) + (k0<<1);
        *(u16x8*)((char*)As + (byte ^ ((row&7)<<4))) = v;
      }
      for (int c = t; c < 512; c += 256){
        int kb = c >> 4, nb = c & 15;
        const float* p = &wqkv[(kb*4)*384 + n0 + nb*4];
        f4 r0 = *(const f4*)p;
        f4 r1 = *(const f4*)(p + 384);
        f4 r2 = *(const f4*)(p + 768);
        f4 r3 = *(const f4*)(p + 1152);
#pragma unroll
        for (int j = 0; j < 4; ++j){
          int n = nb*4 + j;
          uint2v val;
          val[0] = (unsigned int)f2b(r0[j]) | ((unsigned int)f2b(r1[j])<<16);
          val[1] = (unsigned int)f2b(r2[j]) | ((unsigned int)f2b(r3[j])<<16);
          int byte = (n<<8) + (kb<<3);
          *(uint2v*)((char*)Bs + (byte ^ ((n&7)<<4))) = val;
        }
      }
      __syncthreads();
      f32x4 acc[4] = {};
#pragma unroll
      for (int k0 = 0; k0 < 4; ++k0){
        int koff = k0*32 + lk;
        int row = wv*16 + lr;
        int byte = (row<<8) + (koff<<1);
        short8 a = *(const short8*)((const char*)As + (byte ^ ((row&7)<<4)));
#pragma unroll
        for (int fn = 0; fn < 4; ++fn)
          acc[fn] = __builtin_amdgcn_mfma_f32_16x16x32_bf16(a, ldB(Bs, fn*16+lr, koff), acc[fn], 0, 0, 0);
      }
      __syncthreads();
      short* C = As;                       // [64][72] bf16
      float scale = (plane == 0) ? QSCALE : 1.0f;
#pragma unroll
      for (int fn = 0; fn < 4; ++fn){
        int col = fn*16 + lr;
        float bv = bqkv[n0 + col];
#pragma unroll
        for (int r = 0; r < 4; ++r){
          int row = wv*16 + ((l>>4)<<2) + r;
          C[row*72 + col] = f2b((acc[fn][r] + bv) * scale);
        }
      }
      __syncthreads();
      unsigned short* dst = plane==0 ? qo : (plane==1 ? ko : vo);
      for (int c = t; c < 512; c += 256){
        int row = c >> 3, cc = (c & 7) << 3;
        int ch = nh*64 + cc;
        int head = ch >> 5, d0 = ch & 31;
        *(u16x8*)&dst[(head*16384 + m0 + row)*32 + d0] = *(u16x8*)&C[row*72 + cc];
      }
      __syncthreads();
    }
  }
  grid_barrier(&cnt[0]);

  // ======== phase 2: attention, 1024 units (tile, batch, head) ========
  // q staged in LDS (not regs) -> live set ~70 VGPR, no spill at the 128 cap.
  {
    unsigned short* ks = (unsigned short*)smem;           // [196][40]
    unsigned short* vs = (unsigned short*)smem + 7840;    // [196][40]
    unsigned short* qs = (unsigned short*)smem + 15680;   // [64][40]
    float* rs = (float*)(smem + 18240);                   // [169]
#pragma unroll 1
    for (int k2 = 0; k2 < 2; ++k2){
      int u = bid + k2*512;
      int b = u >> 8, h = (u >> 6) & 3, ty = (u >> 3) & 7, tx = u & 7;
      int th0 = ty*8, tw0 = tx*8;
      int bi0 = min(max(th0-3,0),50), bj0 = min(max(tw0-3,0),50);
      const unsigned short* kpb = ko + (h*16384 + b*4096)*32;
      const unsigned short* vpb = vo + (h*16384 + b*4096)*32;
      for (int c = t; c < 784; c += 256){
        int tok = c >> 2, ch = c & 3;
        int trow = tok/14, tcol = tok - trow*14;
        int g = ((bi0+trow)*64 + (bj0+tcol))*32 + ch*8;
        int lo2 = tok*40 + ch*8;
        *(u16x8*)&ks[lo2] = *(const u16x8*)&kpb[g];
        *(u16x8*)&vs[lo2] = *(const u16x8*)&vpb[g];
      }
      {
        int tok = t >> 2, ch = t & 3;    // 256 threads = 64 tok x 4 chunks
        int gq = (h*16384 + b*4096 + (th0+(tok>>3))*64 + tw0+(tok&7))*32 + ch*8;
        *(u16x8*)&qs[tok*40 + ch*8] = *(const u16x8*)&qo[gq];
      }
      for (int c = t; c < 169; c += 256) rs[c] = rpb[h*169 + c];
      __syncthreads();

      const int lt = t >> 2, p = t & 3;
      const int ti = th0 + (lt >> 3), tj = tw0 + (lt & 7);
      const int si = min(max(ti-3,0),57), sj = min(max(tj-3,0),57);
      const int li = si - bi0, lj = sj - bj0;
      const int ri = si - ti + 6, rj = sj - tj + 6;
      const int tbase = li*14 + lj;
      const int rbase = ri*13 + rj;

      float s[13];
      float mx = -1e30f;
#pragma unroll
      for (int it = 0; it < 13; ++it){
        int n = p + (it << 2);
        bool ok = (n < 49);
        int nn = ok ? n : 48;
        int pi = nn / 7, pj = nn - pi*7;
        int tok = tbase + pi*14 + pj;
        float acc = rs[rbase + pi*13 + pj];
#pragma unroll
        for (int j = 0; j < 4; ++j){
          u16x8 qq = *(const u16x8*)&qs[lt*40 + j*8];
          u16x8 kk = *(const u16x8*)&ks[tok*40 + j*8];
#pragma unroll
          for (int e = 0; e < 8; ++e) acc += b2f(qq[e])*b2f(kk[e]);
        }
        s[it] = ok ? acc : -1e30f;
        mx = fmaxf(mx, s[it]);
      }
      mx = fmaxf(mx, __shfl_xor(mx, 1));
      mx = fmaxf(mx, __shfl_xor(mx, 2));

      float lsum = 0.f, o[32];
#pragma unroll
      for (int d = 0; d < 32; ++d) o[d] = 0.f;
#pragma unroll
      for (int it = 0; it < 13; ++it){
        int n = p + (it << 2);
        int nn = n < 49 ? n : 48;
        int pi = nn / 7, pj = nn - pi*7;
        int tok = tbase + pi*14 + pj;
        float e = __expf(s[it] - mx);
        lsum += e;
#pragma unroll
        for (int j = 0; j < 4; ++j){
          u16x8 vvv = *(const u16x8*)&vs[tok*40 + j*8];
#pragma unroll
          for (int e2 = 0; e2 < 8; ++e2) o[j*8+e2] += e*b2f(vvv[e2]);
        }
      }
      lsum += __shfl_xor(lsum, 1);
      lsum += __shfl_xor(lsum, 2);
#pragma unroll
      for (int d = 0; d < 32; ++d) o[d] += __shfl_xor(o[d], 1);
#pragma unroll
      for (int d = 0; d < 32; ++d) o[d] += __shfl_xor(o[d], 2);

      float inv = 1.f / lsum;
      {
        u16x8 w8;
#pragma unroll
        for (int e = 0; e < 8; ++e) w8[e] = f2b(o[p*8+e]*inv);
        *(u16x8*)&ao[(b*4096 + ti*64 + tj)*128 + h*32 + p*8] = w8;
      }
      __syncthreads();
    }
  }
  grid_barrier(&cnt[1]);

  // ======== phase 3: out = ao @ w_proj + b_proj, 512 units ========
  {
    int m0 = (bid >> 1) << 6, nh = bid & 1, n0 = nh << 6;
    short* As = smem;
    short* Bs = smem + 8192;
    for (int c = t; c < 1024; c += 256){
      int row = c >> 4, k0 = (c & 15) << 3;
      u16x8 v = *(const u16x8*)&ao[(m0+row)*128 + k0];
      int byte = (row<<8) + (k0<<1);
      *(u16x8*)((char*)As + (byte ^ ((row&7)<<4))) = v;
    }
    for (int c = t; c < 512; c += 256){
      int kb = c >> 4, nb = c & 15;
      const float* p = &wproj[(kb*4)*128 + n0 + nb*4];
      f4 r0 = *(const f4*)p;
      f4 r1 = *(const f4*)(p + 128);
      f4 r2 = *(const f4*)(p + 256);
      f4 r3 = *(const f4*)(p + 384);
#pragma unroll
      for (int j = 0; j < 4; ++j){
        int n = nb*4 + j;
        uint2v val;
        val[0] = (unsigned int)f2b(r0[j]) | ((unsigned int)f2b(r1[j])<<16);
        val[1] = (unsigned int)f2b(r2[j]) | ((unsigned int)f2b(r3[j])<<16);
        int byte = (n<<8) + (kb<<3);
        *(uint2v*)((char*)Bs + (byte ^ ((n&7)<<4))) = val;
      }
    }
    __syncthreads();
    f32x4 acc[4] = {};
#pragma unroll
    for (int k0 = 0; k0 < 4; ++k0){
      int koff = k0*32 + lk;
      int row = wv*16 + lr;
      int byte = (row<<8) + (koff<<1);
      short8 a = *(const short8*)((const char*)As + (byte ^ ((row&7)<<4)));
#pragma unroll
      for (int fn = 0; fn < 4; ++fn)
        acc[fn] = __builtin_amdgcn_mfma_f32_16x16x32_bf16(a, ldB(Bs, fn*16+lr, koff), acc[fn], 0, 0, 0);
    }
    __syncthreads();
    float* C = (float*)smem;   // [64][68] fp32
#pragma unroll
    for (int fn = 0; fn < 4; ++fn){
      int col = fn*16 + lr;
      float bv = bproj[n0 + col];
#pragma unroll
      for (int r = 0; r < 4; ++r){
        int row = wv*16 + ((l>>4)<<2) + r;
        C[row*68 + col] = acc[fn][r] + bv;
      }
    }
    __syncthreads();
    for (int c = t; c < 1024; c += 256){
      int row = c >> 4, colc = (c & 15) << 2;
      *(f4*)&out[(m0+row)*128 + n0 + colc] = *(const f4*)&C[row*68 + colc];
    }
  }
}

extern "C" void kernel_launch(void* const* d_in, const int* in_sizes, int n_in,
                              void* d_out, int out_size, void* d_ws, size_t ws_size,
                              hipStream_t stream) {
  const float* x      = (const float*)d_in[0];
  const float* wqkv   = (const float*)d_in[1];
  const float* bqkv   = (const float*)d_in[2];
  const float* rpb    = (const float*)d_in[3];
  const float* wproj  = (const float*)d_in[4];
  const float* bproj  = (const float*)d_in[5];
  float* out = (float*)d_out;

  unsigned short* qo = (unsigned short*)d_ws;          // [4 head][16384 tok][32]
  unsigned short* ko = qo + 16384*32*4;
  unsigned short* vo = ko + 16384*32*4;
  unsigned short* ao = vo + 16384*32*4;                // [16384 tok][128]
  unsigned int*  cnt = (unsigned int*)(ao + 16384*128);

  hipMemsetAsync(cnt, 0, 2*sizeof(unsigned int), stream);
  k_pipe<<<512, 256, 0, stream>>>(x, wqkv, bqkv, rpb, wproj, bproj, out,
                                  qo, ko, vo, ao, cnt);
}